// Round 1
// 921.011 us; speedup vs baseline: 1.0625x; 1.0625x over previous
//
#include <hip/hip_runtime.h>
#include <hip/hip_bf16.h>
#include <math.h>

// Problem: B=2, S=2048, D=4096, H=32, KV=8, HD=128, N_REP=4, theta=1e6
// Output fp32 (2,2048,4096).

typedef __bf16 bf16;
typedef __attribute__((ext_vector_type(8))) __bf16 bf16x8;
typedef __attribute__((ext_vector_type(4))) float f32x4;

// async global->LDS, 16 B per lane; LDS dest = wave-uniform base + lane*16
__device__ __forceinline__ void glds16(const void* g, void* l) {
    __builtin_amdgcn_global_load_lds(
        (const __attribute__((address_space(1))) void*)g,
        (__attribute__((address_space(3))) void*)l, 16, 0, 0);
}

// ---------------------------------------------------------------------------
// fp32 -> bf16 elementwise convert (hidden), 8 elems/thread
// ---------------------------------------------------------------------------
__global__ __launch_bounds__(256) void convert_kernel(
    const float* __restrict__ in, bf16* __restrict__ out)
{
    const size_t i0 = ((size_t)blockIdx.x * 256 + threadIdx.x) * 8;
    const float4 a = *(const float4*)(in + i0);
    const float4 b = *(const float4*)(in + i0 + 4);
    bf16x8 p;
    p[0] = (bf16)a.x; p[1] = (bf16)a.y; p[2] = (bf16)a.z; p[3] = (bf16)a.w;
    p[4] = (bf16)b.x; p[5] = (bf16)b.y; p[6] = (bf16)b.z; p[7] = (bf16)b.w;
    *(bf16x8*)(out + i0) = p;
}

// ---------------------------------------------------------------------------
// Weight transpose + fp32->bf16: in [K=4096][N] row-major -> out [N][4096].
// ---------------------------------------------------------------------------
__global__ __launch_bounds__(256) void transpose_conv_kernel(
    const float* __restrict__ in, bf16* __restrict__ out, int N)
{
    __shared__ bf16 tile[32 * 68];
    const int n0 = blockIdx.x * 32, k0 = blockIdx.y * 64;
    const int t = threadIdx.x;
    const int nn = t & 31, kk0 = (t >> 5) * 8;
#pragma unroll
    for (int j = 0; j < 8; ++j)
        tile[nn * 68 + kk0 + j] = (bf16)in[(size_t)(k0 + kk0 + j) * N + n0 + nn];
    __syncthreads();
    const int n2 = t >> 3, c = (t & 7) * 8;
    *(bf16x8*)(out + (size_t)(n0 + n2) * 4096 + k0 + c) = *(const bf16x8*)(&tile[n2 * 68 + c]);
}

// ---------------------------------------------------------------------------
// GEMM m97-style: C[4096,N] = A[4096,4096] * B^T[N][4096] (+bias).
// Tile 128x128, BK=32, 4 waves (2x2), wave 64x64 (4x4 MFMAs), glds staging.
// EPI 0: bias + q->[b,s,h,d], k/v scattered ->[b,kv,s,d] (bf16)
// EPI 1: fp32 out.  AF32: A staged from fp32 via VALU (fallback path only).
// ---------------------------------------------------------------------------
template <int EPI, int AF32>
__global__ __launch_bounds__(256) void gemm_kernel(
    const float* __restrict__ A_f32, const bf16* __restrict__ A_bf16,
    const bf16* __restrict__ BqT, const bf16* __restrict__ BkT, const bf16* __restrict__ BvT,
    const float* __restrict__ b_q, const float* __restrict__ b_k, const float* __restrict__ b_v,
    bf16* __restrict__ q_out, bf16* __restrict__ kv_k, bf16* __restrict__ kv_v,
    float* __restrict__ f_out)
{
    constexpr int LDA = AF32 ? 34 : 32;
    __shared__ bf16 As[128 * LDA];
    __shared__ bf16 Bs[128 * 32];

    const int nt = blockIdx.x, mt = blockIdx.y;
    const int tid = threadIdx.x;
    const int wave = tid >> 6, lane = tid & 63;
    const int l15 = lane & 15, quad = lane >> 4;
    const int wm = (wave >> 1) * 64, wn = (wave & 1) * 64;

    const bf16* BT;
    const float* bias = nullptr;
    int sel = 0, ncol0;
    if (EPI == 0) {
        if (nt < 32)      { BT = BqT; bias = b_q; sel = 0; ncol0 = nt * 128; }
        else if (nt < 40) { BT = BkT; bias = b_k; sel = 1; ncol0 = (nt - 32) * 128; }
        else              { BT = BvT; bias = b_v; sel = 2; ncol0 = (nt - 40) * 128; }
    } else {
        BT = BqT; ncol0 = nt * 128;
    }
    const int row0 = mt * 128;

    const f32x4 vzero = {0.f, 0.f, 0.f, 0.f};
    f32x4 acc[4][4];
#pragma unroll
    for (int mi = 0; mi < 4; ++mi)
#pragma unroll
        for (int ni = 0; ni < 4; ++ni) acc[mi][ni] = vzero;

    const int a_row = tid >> 1, a_seg = (tid & 1) * 16;   // AF32 VALU staging
    const int g_row = lane >> 2, g_seg = (lane & 3) * 8;  // glds lane mapping

    for (int k0 = 0; k0 < 4096; k0 += 32) {
        // ---- stage A tile (128x32) ----
        if (AF32) {
            const float4* src = (const float4*)(A_f32 + (size_t)(row0 + a_row) * 4096 + k0 + a_seg);
            float4 f0 = src[0], f1 = src[1], f2 = src[2], f3 = src[3];
            bf16x8 p0, p1;
            p0[0] = (bf16)f0.x; p0[1] = (bf16)f0.y; p0[2] = (bf16)f0.z; p0[3] = (bf16)f0.w;
            p0[4] = (bf16)f1.x; p0[5] = (bf16)f1.y; p0[6] = (bf16)f1.z; p0[7] = (bf16)f1.w;
            p1[0] = (bf16)f2.x; p1[1] = (bf16)f2.y; p1[2] = (bf16)f2.z; p1[3] = (bf16)f2.w;
            p1[4] = (bf16)f3.x; p1[5] = (bf16)f3.y; p1[6] = (bf16)f3.z; p1[7] = (bf16)f3.w;
            *(bf16x8*)(&As[a_row * LDA + a_seg]) = p0;
            *(bf16x8*)(&As[a_row * LDA + a_seg + 8]) = p1;
        } else {
#pragma unroll
            for (int c = 0; c < 2; ++c)
                glds16(A_bf16 + (size_t)(row0 + wave * 32 + c * 16 + g_row) * 4096 + k0 + g_seg,
                       &As[(wave * 32 + c * 16) * 32]);
        }
        // ---- stage B^T tile (128 n-rows x 32 k) via glds ----
#pragma unroll
        for (int c = 0; c < 2; ++c)
            glds16(BT + (size_t)(ncol0 + wave * 32 + c * 16 + g_row) * 4096 + k0 + g_seg,
                   &Bs[(wave * 32 + c * 16) * 32]);
        __syncthreads();

        bf16x8 af[4], bfv[4];
#pragma unroll
        for (int mi = 0; mi < 4; ++mi)
            af[mi] = *(const bf16x8*)(&As[(wm + mi * 16 + l15) * LDA + quad * 8]);
#pragma unroll
        for (int ni = 0; ni < 4; ++ni)
            bfv[ni] = *(const bf16x8*)(&Bs[(wn + ni * 16 + l15) * 32 + quad * 8]);
#pragma unroll
        for (int mi = 0; mi < 4; ++mi)
#pragma unroll
            for (int ni = 0; ni < 4; ++ni)
                acc[mi][ni] = __builtin_amdgcn_mfma_f32_16x16x32_bf16(af[mi], bfv[ni], acc[mi][ni], 0, 0, 0);
        __syncthreads();
    }

    // ---- epilogue: C row = quad*4+reg, col = l15 ----
#pragma unroll
    for (int mi = 0; mi < 4; ++mi)
#pragma unroll
        for (int ni = 0; ni < 4; ++ni)
#pragma unroll
            for (int i = 0; i < 4; ++i) {
                const int gr = row0 + wm + mi * 16 + quad * 4 + i;
                const int gc = ncol0 + wn + ni * 16 + l15;
                float vv = acc[mi][ni][i];
                if (EPI == 1) {
                    f_out[(size_t)gr * 4096 + gc] = vv;
                } else {
                    vv += bias[gc];
                    if (sel == 0) {
                        q_out[(size_t)gr * 4096 + gc] = (bf16)vv;  // [b,s,h,d]
                    } else {
                        bf16* dst = (sel == 1) ? kv_k : kv_v;      // [b,kv,s,d]
                        dst[(size_t)((gr >> 11) * 8 + (gc >> 7)) * 262144 +
                            (size_t)(gr & 2047) * 128 + (gc & 127)] = (bf16)vv;
                    }
                }
            }
}

// ---------------------------------------------------------------------------
// In-place RoPE. Q [b,s,h,128] (scale folded); K [b,kv,s,128].
// ---------------------------------------------------------------------------
__global__ __launch_bounds__(256) void rope_q_kernel(
    bf16* __restrict__ q, const int* __restrict__ pos_ids)
{
    const int idx = blockIdx.x * 256 + threadIdx.x;
    const int d = idx & 63, h = (idx >> 6) & 31, tok = idx >> 11;
    const float posv = (float)pos_ids[tok];
    const float fr = exp2f((float)d * (-19.931568569324174f / 64.f));
    float sn, cs;
    sincosf(posv * fr, &sn, &cs);
    bf16* xp = q + (size_t)tok * 4096 + h * 128 + d;
    const float x1 = (float)xp[0], x2 = (float)xp[64];
    const float scale = 0.08838834764831845f;
    xp[0]  = (bf16)((x1 * cs - x2 * sn) * scale);
    xp[64] = (bf16)((x1 * sn + x2 * cs) * scale);
}

__global__ __launch_bounds__(256) void rope_k_kernel(
    bf16* __restrict__ k, const int* __restrict__ pos_ids)
{
    const int idx = blockIdx.x * 256 + threadIdx.x;
    const int d = idx & 63, s = (idx >> 6) & 2047, bk = idx >> 17;
    const int b = bk >> 3;
    const float posv = (float)pos_ids[b * 2048 + s];
    const float fr = exp2f((float)d * (-19.931568569324174f / 64.f));
    float sn, cs;
    sincosf(posv * fr, &sn, &cs);
    bf16* xp = k + ((size_t)bk * 2048 + s) * 128 + d;
    const float x1 = (float)xp[0], x2 = (float)xp[64];
    xp[0]  = (bf16)(x1 * cs - x2 * sn);
    xp[64] = (bf16)(x1 * sn + x2 * cs);
}

// ---------------------------------------------------------------------------
// Flash attention, causal, GQA. 4 waves, wave owns 32 q-rows (2 m-tiles).
// KV tiles of 64. K/V frags shared across m-tiles (joint loops).
// V staged transposed with lane=kv-row (2-way banks = free). P stride 68.
// No P barrier (wave-local LDS round-trip, lgkmcnt-ordered).
//
// WORK BALANCING: causal triangle means q-tile qt does 2*qt+2 KV tile-steps
// (2..32, a 16:1 spread). Each block now processes the PAIR (pair, 15-pair):
// every block does exactly 34 tile-steps, grid = 512 (2 blocks/CU, all
// co-resident, uniform finish -> no idle tail).
// ---------------------------------------------------------------------------
__global__ __launch_bounds__(256) void attn_kernel(
    const bf16* __restrict__ q, const bf16* __restrict__ k,
    const bf16* __restrict__ v, bf16* __restrict__ o)
{
    __shared__ bf16 Ksl[64 * 136];      // [kv][d]
    __shared__ bf16 Vsl[128 * 72];      // [d][kv]
    __shared__ bf16 Psl[4 * 16 * 68];   // per-wave [qrow][kv]

    const int pair = blockIdx.x & 7;
    const int h  = (blockIdx.x >> 3) & 31;
    const int b  = blockIdx.x >> 8;
    const int kvh = h >> 2;
    const int tid = threadIdx.x;
    const int wave = tid >> 6, lane = tid & 63;
    const int l15 = lane & 15, quad = lane >> 4;

    const bf16* kbase = k + (size_t)(b * 8 + kvh) * 2048 * 128;
    const bf16* vbase = v + (size_t)(b * 8 + kvh) * 2048 * 128;

    const int kr = tid >> 2, ksg = (tid & 3) * 32;  // K staging: 64 rows x 4 segs
    const f32x4 vzero = {0.f, 0.f, 0.f, 0.f};

#pragma unroll 1
    for (int phase = 0; phase < 2; ++phase) {
        const int qt = phase ? (15 - pair) : pair;
        const int qbase = qt * 128 + wave * 32;

        // Q fragments, 2 m-tiles (A-layout: row=l15, k=quad*8+j)
        bf16x8 qf[2][4];
#pragma unroll
        for (int mi = 0; mi < 2; ++mi) {
            const bf16* qrow = q + ((size_t)(b * 2048 + qbase + mi * 16 + l15) * 32 + h) * 128;
#pragma unroll
            for (int kb = 0; kb < 4; ++kb)
                qf[mi][kb] = *(const bf16x8*)(qrow + kb * 32 + quad * 8);
        }

        f32x4 acc_o[2][8];
#pragma unroll
        for (int mi = 0; mi < 2; ++mi)
#pragma unroll
            for (int i = 0; i < 8; ++i) acc_o[mi][i] = vzero;
        float m_i[2][4], l_i[2][4];
#pragma unroll
        for (int mi = 0; mi < 2; ++mi)
#pragma unroll
            for (int i = 0; i < 4; ++i) { m_i[mi][i] = -INFINITY; l_i[mi][i] = 0.f; }

        const int nT = 2 * qt + 2;
        for (int t = 0; t < nT; ++t) {
            const int kv0 = t * 64;
            // ---- stage K row-major (b128, conflict-min) ----
            {
                const bf16x8* ks = (const bf16x8*)(kbase + (size_t)(kv0 + kr) * 128 + ksg);
                bf16x8* kd = (bf16x8*)(&Ksl[kr * 136 + ksg]);
                kd[0] = ks[0]; kd[1] = ks[1]; kd[2] = ks[2]; kd[3] = ks[3];
            }
            // ---- stage V transposed: wave=d-block, lane=kv row -> 2-way banks ----
            {
                const bf16x8* vs = (const bf16x8*)(vbase + (size_t)(kv0 + lane) * 128 + wave * 32);
                bf16x8 w0 = vs[0], w1 = vs[1], w2 = vs[2], w3 = vs[3];
#pragma unroll
                for (int i = 0; i < 8; ++i) {
                    Vsl[(wave * 32 + i)      * 72 + lane] = w0[i];
                    Vsl[(wave * 32 + 8 + i)  * 72 + lane] = w1[i];
                    Vsl[(wave * 32 + 16 + i) * 72 + lane] = w2[i];
                    Vsl[(wave * 32 + 24 + i) * 72 + lane] = w3[i];
                }
            }
            __syncthreads();

            if (kv0 <= qbase + 31) {  // wave has unmasked work in this tile
                // ---- S = Q K^T, joint over m-tiles (K frag read once) ----
                f32x4 sacc[2][4];
#pragma unroll
                for (int mi = 0; mi < 2; ++mi)
#pragma unroll
                    for (int nt = 0; nt < 4; ++nt) sacc[mi][nt] = vzero;
#pragma unroll
                for (int nt = 0; nt < 4; ++nt)
#pragma unroll
                    for (int kb = 0; kb < 4; ++kb) {
                        const bf16x8 kf = *(const bf16x8*)(&Ksl[(nt * 16 + l15) * 136 + kb * 32 + quad * 8]);
                        sacc[0][nt] = __builtin_amdgcn_mfma_f32_16x16x32_bf16(qf[0][kb], kf, sacc[0][nt], 0, 0, 0);
                        sacc[1][nt] = __builtin_amdgcn_mfma_f32_16x16x32_bf16(qf[1][kb], kf, sacc[1][nt], 0, 0, 0);
                    }

                // ---- per-m-tile softmax + P write ----
                bf16x8 pf[2][2];
#pragma unroll
                for (int mi = 0; mi < 2; ++mi) {
                    const int rb = qbase + mi * 16;
                    if (kv0 + 63 > rb) {  // diagonal tile: apply causal mask
#pragma unroll
                        for (int nt = 0; nt < 4; ++nt) {
                            const int kvc = kv0 + nt * 16 + l15;
#pragma unroll
                            for (int i = 0; i < 4; ++i)
                                if (kvc > rb + quad * 4 + i) sacc[mi][nt][i] = -INFINITY;
                        }
                    }
                    float mt_[4];
#pragma unroll
                    for (int i = 0; i < 4; ++i)
                        mt_[i] = fmaxf(fmaxf(sacc[mi][0][i], sacc[mi][1][i]),
                                       fmaxf(sacc[mi][2][i], sacc[mi][3][i]));
#pragma unroll
                    for (int off = 1; off < 16; off <<= 1)
#pragma unroll
                        for (int i = 0; i < 4; ++i)
                            mt_[i] = fmaxf(mt_[i], __shfl_xor(mt_[i], off, 64));

                    float alpha[4];
#pragma unroll
                    for (int i = 0; i < 4; ++i) {
                        const float mnew = fmaxf(m_i[mi][i], mt_[i]);
                        alpha[i] = __expf(m_i[mi][i] - mnew);
                        m_i[mi][i] = mnew;
                    }
                    float rs[4] = {0.f, 0.f, 0.f, 0.f};
#pragma unroll
                    for (int nt = 0; nt < 4; ++nt)
#pragma unroll
                        for (int i = 0; i < 4; ++i) {
                            const float pv = __expf(sacc[mi][nt][i] - m_i[mi][i]);
                            rs[i] += pv;
                            Psl[wave * 1088 + (quad * 4 + i) * 68 + nt * 16 + l15] = (bf16)pv;
                        }
#pragma unroll
                    for (int off = 1; off < 16; off <<= 1)
#pragma unroll
                        for (int i = 0; i < 4; ++i)
                            rs[i] += __shfl_xor(rs[i], off, 64);
#pragma unroll
                    for (int i = 0; i < 4; ++i) l_i[mi][i] = l_i[mi][i] * alpha[i] + rs[i];
#pragma unroll
                    for (int dn = 0; dn < 8; ++dn)
#pragma unroll
                        for (int i = 0; i < 4; ++i) acc_o[mi][dn][i] *= alpha[i];
                    // P -> A-layout frags (wave-local; lgkmcnt orders write->read)
#pragma unroll
                    for (int k2 = 0; k2 < 2; ++k2)
                        pf[mi][k2] = *(const bf16x8*)(&Psl[wave * 1088 + l15 * 68 + k2 * 32 + quad * 8]);
                }

                // ---- O += P V, joint over m-tiles (V frag read once) ----
#pragma unroll
                for (int dn = 0; dn < 8; ++dn)
#pragma unroll
                    for (int k2 = 0; k2 < 2; ++k2) {
                        const bf16x8 vf = *(const bf16x8*)(&Vsl[(dn * 16 + l15) * 72 + k2 * 32 + quad * 8]);
                        acc_o[0][dn] = __builtin_amdgcn_mfma_f32_16x16x32_bf16(pf[0][k2], vf, acc_o[0][dn], 0, 0, 0);
                        acc_o[1][dn] = __builtin_amdgcn_mfma_f32_16x16x32_bf16(pf[1][k2], vf, acc_o[1][dn], 0, 0, 0);
                    }
            }
            __syncthreads();
        }

        // ---- epilogue -> [b,s,h,d] (register-only; LDS safe for next phase) ----
#pragma unroll
        for (int mi = 0; mi < 2; ++mi) {
            float inv[4];
#pragma unroll
            for (int i = 0; i < 4; ++i) inv[i] = 1.f / l_i[mi][i];
#pragma unroll
            for (int dn = 0; dn < 8; ++dn)
#pragma unroll
                for (int i = 0; i < 4; ++i) {
                    const int s = qbase + mi * 16 + quad * 4 + i;
                    o[(((size_t)b * 2048 + s) * 32 + h) * 128 + dn * 16 + l15] =
                        (bf16)(acc_o[mi][dn][i] * inv[i]);
                }
        }
    }
}

// ---------------------------------------------------------------------------
extern "C" void kernel_launch(void* const* d_in, const int* in_sizes, int n_in,
                              void* d_out, int out_size, void* d_ws, size_t ws_size,
                              hipStream_t stream)
{
    (void)in_sizes; (void)n_in; (void)out_size;
    const float* hidden = (const float*)d_in[0];
    const int*   pos    = (const int*)d_in[1];
    const float* wq     = (const float*)d_in[2];
    const float* bq_    = (const float*)d_in[3];
    const float* wk     = (const float*)d_in[4];
    const float* bk_    = (const float*)d_in[5];
    const float* wv     = (const float*)d_in[6];
    const float* bv_    = (const float*)d_in[7];
    const float* wo     = (const float*)d_in[8];
    float* out = (float*)d_out;

    char* ws = (char*)d_ws;
    bf16* wqT   = (bf16*)(ws);                 // 33.5 MB -> attn_o after QKV
    bf16* wkT   = (bf16*)(ws + 33554432);      //  8.4 MB
    bf16* wvT   = (bf16*)(ws + 41943040);      //  8.4 MB
    bf16* q_pre = (bf16*)(ws + 50331648);      // 33.5 MB -> woT after attn
    bf16* k_t   = (bf16*)(ws + 83886080);      //  8.4 MB [b,kv,s,d]
    bf16* v_t   = (bf16*)(ws + 92274688);      //  8.4 MB [b,kv,s,d]
    bf16* hid_b = (bf16*)(ws + 100663296);     // 33.5 MB (if ws allows)
    bf16* attn_o = wqT;
    bf16* woT    = q_pre;
    const bool have_hid = (ws_size >= 134217728);

    // 1) weight transposes (fp32 [K][N] -> bf16 [N][K])
    transpose_conv_kernel<<<dim3(128, 64), 256, 0, stream>>>(wq, wqT, 4096);
    transpose_conv_kernel<<<dim3(32, 64), 256, 0, stream>>>(wk, wkT, 1024);
    transpose_conv_kernel<<<dim3(32, 64), 256, 0, stream>>>(wv, wvT, 1024);

    // 2) QKV projection; K/V written directly to [b,kv,s,d]
    if (have_hid) {
        convert_kernel<<<8192, 256, 0, stream>>>(hidden, hid_b);
        gemm_kernel<0, 0><<<dim3(48, 32), 256, 0, stream>>>(
            nullptr, hid_b, wqT, wkT, wvT, bq_, bk_, bv_, q_pre, k_t, v_t, nullptr);
    } else {
        gemm_kernel<0, 1><<<dim3(48, 32), 256, 0, stream>>>(
            hidden, nullptr, wqT, wkT, wvT, bq_, bk_, bv_, q_pre, k_t, v_t, nullptr);
    }

    // 3) in-place RoPE (Q gets 1/sqrt(128) folded)
    rope_q_kernel<<<32768, 256, 0, stream>>>(q_pre, pos);
    rope_k_kernel<<<8192, 256, 0, stream>>>(k_t, pos);

    // 4) causal GQA flash attention, balanced q-tile pairs -> attn_o [b,s,h,d]
    attn_kernel<<<512, 256, 0, stream>>>(q_pre, k_t, v_t, attn_o);

    // 5) transpose wo into q_pre region (q dead after attn)
    transpose_conv_kernel<<<dim3(128, 64), 256, 0, stream>>>(wo, woT, 4096);

    // 6) output projection -> d_out (fp32)
    gemm_kernel<1, 0><<<dim3(32, 32), 256, 0, stream>>>(
        nullptr, attn_o, woT, nullptr, nullptr, nullptr, nullptr, nullptr,
        nullptr, nullptr, nullptr, out);
}